// Round 2
// baseline (535.424 us; speedup 1.0000x reference)
//
#include <hip/hip_runtime.h>
#include <hip/hip_bf16.h>

// GraphVertEdgeNet on MI355X. B=64, N=64, VF=32, EF=16, DV=DE=128, LN=4.
// e stored bf16 in ws (64MB). Edge kernels use transposed MFMA orientation
// D[c][i] so the accumulator holds 4 consecutive c per thread -> vectorized
// (b64) epilogue instead of scalar 2B LDS RMW.

typedef __bf16 bf16_t;
typedef __bf16 bf16x8 __attribute__((ext_vector_type(8)));
typedef __bf16 bf16x4 __attribute__((ext_vector_type(4)));
typedef float f32x4 __attribute__((ext_vector_type(4)));

// ---------------- input batchnorm: BatchNorm1d(N*VF) over batch ----------------
__global__ __launch_bounds__(256) void k_bn_in(const float* __restrict__ vin,
    const float* __restrict__ g, const float* __restrict__ bt,
    float* __restrict__ v0) {
  int ch = blockIdx.x * 256 + threadIdx.x;  // 0..2047
  float s = 0.f, s2 = 0.f;
  for (int b = 0; b < 64; ++b) { float x = vin[b * 2048 + ch]; s += x; s2 += x * x; }
  float mu = s * (1.f / 64.f);
  float var = s2 * (1.f / 64.f) - mu * mu;   // biased var (jnp default)
  float sc = rsqrtf(var + 1e-5f) * g[ch];
  float bb = bt[ch];
  for (int b = 0; b < 64; ++b) {
    float x = vin[b * 2048 + ch];
    v0[b * 2048 + ch] = (x - mu) * sc + bb;
  }
}

// ------------- weight prep: Wt[l][n][k] = eW[l][k][n] as bf16 -------------
__global__ __launch_bounds__(256) void k_prep_wt(const float* __restrict__ eW,
    bf16_t* __restrict__ Wt) {
  int idx = blockIdx.x * 256 + threadIdx.x;  // 4*128*128 = 65536
  int l = idx >> 14, r = idx & 16383, n = r >> 7, k = r & 127;
  Wt[idx] = (bf16_t)eW[(l << 14) + (k << 7) + n];
}

// ------------- ev = v_in @ W + bias : [4096,K] @ [K,128] -> [4096,128] -------------
template <int K>
__global__ __launch_bounds__(128) void k_ev(const float* __restrict__ v_in,
    const float* __restrict__ W, const float* __restrict__ bias,
    float* __restrict__ out) {
  __shared__ float rows[8][K];
  const int r0 = blockIdx.x * 8;
  const int c = threadIdx.x;  // 128 threads
  for (int idx = c; idx < 8 * K; idx += 128) {
    int rr = idx / K, kk = idx % K;
    rows[rr][kk] = v_in[(r0 + rr) * K + kk];
  }
  __syncthreads();
  float acc[8];
  const float bv = bias[c];
#pragma unroll
  for (int r = 0; r < 8; ++r) acc[r] = bv;
  for (int k4 = 0; k4 < K; k4 += 4) {
    float w0 = W[(k4 + 0) * 128 + c], w1 = W[(k4 + 1) * 128 + c];
    float w2 = W[(k4 + 2) * 128 + c], w3 = W[(k4 + 3) * 128 + c];
#pragma unroll
    for (int r = 0; r < 8; ++r) {
      float4 x = *(const float4*)&rows[r][k4];
      acc[r] += x.x * w0 + x.y * w1 + x.z * w2 + x.w * w3;
    }
  }
#pragma unroll
  for (int r = 0; r < 8; ++r) out[(r0 + r) * 128 + c] = acc[r];
}

// ------------- g1 edge pass (MFMA, K padded 16->32): e = relu(e0@eW + eb + ev_i + ev_j) -------------
__global__ __launch_bounds__(256) void k_edge_g1(const float* __restrict__ e0,
    const float* __restrict__ eW, const float* __restrict__ eb,
    const float* __restrict__ ev, bf16_t* __restrict__ e_ws,
    float* __restrict__ pve) {
  __shared__ bf16_t A0s[64][40];   // 32 k (16 real + 16 zero) + 8 pad
  __shared__ bf16_t Os[64][136];
  const int b = blockIdx.x >> 6, j = blockIdx.x & 63;
  const int tid = threadIdx.x;
  const int lane = tid & 63, w = tid >> 6;
  const int quad = lane >> 4, l16 = lane & 15;
  {  // stage e0 column -> bf16, zero-pad K
    int row = tid >> 2, s = (tid & 3) * 4;
    f32x4 x = *(const f32x4*)&e0[((b * 64 + row) * 64 + j) * 16 + s];
    bf16x4 y;
#pragma unroll
    for (int r = 0; r < 4; ++r) y[r] = (bf16_t)x[r];
    *(bf16x4*)&A0s[row][s] = y;
    bf16x4 z = {(bf16_t)0.f, (bf16_t)0.f, (bf16_t)0.f, (bf16_t)0.f};
    *(bf16x4*)&A0s[row][16 + s] = z;
  }
  const int c0[2] = {w * 32 + quad * 4, w * 32 + 16 + quad * 4};
  // W A-frags in registers: A[m=c][k], k = quad*8+jj (zeros for k>=16)
  bf16x8 wf[2];
#pragma unroll
  for (int nt = 0; nt < 2; ++nt) {
    const int c = w * 32 + nt * 16 + l16;
#pragma unroll
    for (int jj = 0; jj < 8; ++jj)
      wf[nt][jj] = (quad < 2) ? (bf16_t)eW[(quad * 8 + jj) * 128 + c] : (bf16_t)0.f;
  }
  // acc init = eb + ev_j (per-c broadcast)
  f32x4 acc[4][2];
#pragma unroll
  for (int nt = 0; nt < 2; ++nt) {
    f32x4 e1 = *(const f32x4*)&eb[c0[nt]];
    f32x4 e2 = *(const f32x4*)&ev[(b * 64 + j) * 128 + c0[nt]];
    f32x4 ej = e1 + e2;
#pragma unroll
    for (int mt = 0; mt < 4; ++mt) acc[mt][nt] = ej;
  }
  __syncthreads();
#pragma unroll
  for (int mt = 0; mt < 4; ++mt) {
    bf16x8 ef = *(const bf16x8*)&A0s[mt * 16 + l16][quad * 8];
#pragma unroll
    for (int nt = 0; nt < 2; ++nt)
      acc[mt][nt] = __builtin_amdgcn_mfma_f32_16x16x32_bf16(wf[nt], ef, acc[mt][nt], 0, 0, 0);
  }
  // epilogue: relu, pve, pack to Os
#pragma unroll
  for (int nt = 0; nt < 2; ++nt) {
    f32x4 ps = {0.f, 0.f, 0.f, 0.f};
#pragma unroll
    for (int mt = 0; mt < 4; ++mt) {
      const int i = mt * 16 + l16;
      f32x4 evi = *(const f32x4*)&ev[(b * 64 + i) * 128 + c0[nt]];
      f32x4 val = acc[mt][nt] + evi;
      bf16x4 outv;
#pragma unroll
      for (int r = 0; r < 4; ++r) {
        float vv = fmaxf(val[r], 0.f);
        ps[r] += vv;
        outv[r] = (bf16_t)vv;
      }
      *(bf16x4*)&Os[i][c0[nt]] = outv;
    }
#pragma unroll
    for (int m = 1; m <= 8; m <<= 1) {
#pragma unroll
      for (int r = 0; r < 4; ++r) ps[r] += __shfl_xor(ps[r], m);
    }
    if (l16 == 0) *(f32x4*)&pve[(b * 64 + j) * 128 + c0[nt]] = ps;
  }
  __syncthreads();
#pragma unroll
  for (int t = 0; t < 4; ++t) {  // coalesced copy-out
    int idx = tid + t * 256;
    int row = idx >> 4, seg = (idx & 15) * 8;
    *(int4*)&e_ws[((b * 64 + row) * 64 + j) * 128 + seg] = *(const int4*)&Os[row][seg];
  }
}

// ------------- g1 v pass: relu(concat(pve[128], v0[32]) @ [160,128]) -------------
__global__ __launch_bounds__(128) void k_v_g1(const float* __restrict__ pve,
    const float* __restrict__ v0, const float* __restrict__ vW,
    const float* __restrict__ vb, float* __restrict__ v) {
  __shared__ float in[8][160];
  const int r0 = blockIdx.x * 8;
  const int c = threadIdx.x;
#pragma unroll
  for (int t = 0; t < 8; ++t) {
    int idx = c + t * 128;
    int rr = idx >> 7, k = idx & 127;
    in[rr][k] = pve[(r0 + rr) * 128 + k];
  }
#pragma unroll
  for (int t = 0; t < 2; ++t) {
    int idx = c + t * 128;
    int rr = idx >> 5, k = idx & 31;
    in[rr][128 + k] = v0[(r0 + rr) * 32 + k];
  }
  __syncthreads();
  float acc[8];
  const float bv = vb[c];
#pragma unroll
  for (int r = 0; r < 8; ++r) acc[r] = bv;
  for (int k4 = 0; k4 < 160; k4 += 4) {
    float w0 = vW[(k4 + 0) * 128 + c], w1 = vW[(k4 + 1) * 128 + c];
    float w2 = vW[(k4 + 2) * 128 + c], w3 = vW[(k4 + 3) * 128 + c];
#pragma unroll
    for (int r = 0; r < 8; ++r) {
      float4 x = *(const float4*)&in[r][k4];
      acc[r] += x.x * w0 + x.y * w1 + x.z * w2 + x.w * w3;
    }
  }
#pragma unroll
  for (int r = 0; r < 8; ++r) v[(r0 + r) * 128 + c] = fmaxf(acc[r], 0.f);
}

// ------------- inner edge pass (MFMA, D[c][i]): e += relu(e@W + eb + ev_i + ev_j) -------------
__global__ __launch_bounds__(256) void k_edge_inner(bf16_t* __restrict__ e_ws,
    const bf16_t* __restrict__ Wt, const float* __restrict__ eb,
    const float* __restrict__ ev, float* __restrict__ pve) {
  __shared__ bf16_t As[64][136];   // +8 pad
  const int b = blockIdx.x >> 6, j = blockIdx.x & 63;
  const int tid = threadIdx.x;
  const int lane = tid & 63, w = tid >> 6;
  const int quad = lane >> 4, l16 = lane & 15;
  // stage e column (loads first, LDS writes after other loads are issued)
  int4 stg[4];
#pragma unroll
  for (int t = 0; t < 4; ++t) {
    int idx = tid + t * 256;
    int row = idx >> 4, seg = (idx & 15) * 8;
    stg[t] = *(const int4*)&e_ws[((b * 64 + row) * 64 + j) * 128 + seg];
  }
  // W A-frags in registers (L2-hot): A[m=c][k]
  bf16x8 wf[2][4];
#pragma unroll
  for (int nt = 0; nt < 2; ++nt)
#pragma unroll
    for (int ks = 0; ks < 4; ++ks)
      wf[nt][ks] = *(const bf16x8*)&Wt[(w * 32 + nt * 16 + l16) * 128 + ks * 32 + quad * 8];
  const int c0[2] = {w * 32 + quad * 4, w * 32 + 16 + quad * 4};
  // e_old prefetch in C-layout (L1-hot: same lines as staging)
  bf16x4 eo[4][2];
#pragma unroll
  for (int mt = 0; mt < 4; ++mt)
#pragma unroll
    for (int nt = 0; nt < 2; ++nt)
      eo[mt][nt] = *(const bf16x4*)&e_ws[((b * 64 + mt * 16 + l16) * 64 + j) * 128 + c0[nt]];
  // acc init = eb + ev_j
  f32x4 acc[4][2];
#pragma unroll
  for (int nt = 0; nt < 2; ++nt) {
    f32x4 e1 = *(const f32x4*)&eb[c0[nt]];
    f32x4 e2 = *(const f32x4*)&ev[(b * 64 + j) * 128 + c0[nt]];
    f32x4 ej = e1 + e2;
#pragma unroll
    for (int mt = 0; mt < 4; ++mt) acc[mt][nt] = ej;
  }
#pragma unroll
  for (int t = 0; t < 4; ++t) {
    int idx = tid + t * 256;
    int row = idx >> 4, seg = (idx & 15) * 8;
    *(int4*)&As[row][seg] = stg[t];
  }
  __syncthreads();
  // MFMA: D[c][i] = sum_k Wt[c][k] * e[i][k]
#pragma unroll
  for (int ks = 0; ks < 4; ++ks) {
    bf16x8 ef[4];
#pragma unroll
    for (int mt = 0; mt < 4; ++mt)
      ef[mt] = *(const bf16x8*)&As[mt * 16 + l16][ks * 32 + quad * 8];
#pragma unroll
    for (int mt = 0; mt < 4; ++mt)
#pragma unroll
      for (int nt = 0; nt < 2; ++nt)
        acc[mt][nt] = __builtin_amdgcn_mfma_f32_16x16x32_bf16(wf[nt][ks], ef[mt], acc[mt][nt], 0, 0, 0);
  }
  __syncthreads();  // all As reads done before in-place update
  // epilogue: relu, pve, residual, packed b64 LDS writes
#pragma unroll
  for (int nt = 0; nt < 2; ++nt) {
    f32x4 ps = {0.f, 0.f, 0.f, 0.f};
#pragma unroll
    for (int mt = 0; mt < 4; ++mt) {
      const int i = mt * 16 + l16;
      f32x4 evi = *(const f32x4*)&ev[(b * 64 + i) * 128 + c0[nt]];
      f32x4 val = acc[mt][nt] + evi;
      bf16x4 outv;
#pragma unroll
      for (int r = 0; r < 4; ++r) {
        float vv = fmaxf(val[r], 0.f);
        ps[r] += vv;                                  // pve is pre-residual
        outv[r] = (bf16_t)(vv + (float)eo[mt][nt][r]);  // residual
      }
      *(bf16x4*)&As[i][c0[nt]] = outv;
    }
#pragma unroll
    for (int m = 1; m <= 8; m <<= 1) {  // sum over i: 4 mt local + 16 l16 lanes
#pragma unroll
      for (int r = 0; r < 4; ++r) ps[r] += __shfl_xor(ps[r], m);
    }
    if (l16 == 0) *(f32x4*)&pve[(b * 64 + j) * 128 + c0[nt]] = ps;
  }
  __syncthreads();
#pragma unroll
  for (int t = 0; t < 4; ++t) {  // coalesced write-back
    int idx = tid + t * 256;
    int row = idx >> 4, seg = (idx & 15) * 8;
    *(int4*)&e_ws[((b * 64 + row) * 64 + j) * 128 + seg] = *(const int4*)&As[row][seg];
  }
}

// ------------- inner v pass: v = relu(concat(pve,v)@[256,128]+vb) + v; BN partial stats -------------
__global__ __launch_bounds__(128) void k_v_inner(const float* __restrict__ pve,
    float* __restrict__ v, const float* __restrict__ vW,
    const float* __restrict__ vb, float* __restrict__ stats) {
  __shared__ float in[8][256];
  __shared__ float outs[8][132];  // +4 pad
  const int r0 = blockIdx.x * 8;
  const int c = threadIdx.x;
#pragma unroll
  for (int t = 0; t < 8; ++t) {
    int idx = c + t * 128;
    int rr = idx >> 7, k = idx & 127;
    in[rr][k] = pve[(r0 + rr) * 128 + k];
    in[rr][128 + k] = v[(r0 + rr) * 128 + k];
  }
  __syncthreads();
  float acc[8];
  const float bv = vb[c];
#pragma unroll
  for (int r = 0; r < 8; ++r) acc[r] = bv;
  for (int k4 = 0; k4 < 256; k4 += 4) {
    float w0 = vW[(k4 + 0) * 128 + c], w1 = vW[(k4 + 1) * 128 + c];
    float w2 = vW[(k4 + 2) * 128 + c], w3 = vW[(k4 + 3) * 128 + c];
#pragma unroll
    for (int r = 0; r < 8; ++r) {
      float4 x = *(const float4*)&in[r][k4];
      acc[r] += x.x * w0 + x.y * w1 + x.z * w2 + x.w * w3;
    }
  }
#pragma unroll
  for (int r = 0; r < 8; ++r) {
    float val = fmaxf(acc[r], 0.f) + in[r][128 + c];  // relu + residual
    outs[r][c] = val;
    v[(r0 + r) * 128 + c] = val;
  }
  __syncthreads();
  if (c < 8) {  // per-(b,n) partial sums for BN stats over (B,D)
    float s = 0.f, s2 = 0.f;
    for (int k = 0; k < 128; ++k) { float x = outs[c][k]; s += x; s2 += x * x; }
    int n = (r0 + c) & 63;
    atomicAdd(&stats[n], s);
    atomicAdd(&stats[64 + n], s2);
  }
}

// ------------- BN-inner apply: channels = n axis, stats over (B,D), eps=128 -------------
__global__ __launch_bounds__(256) void k_bn_apply(float* __restrict__ v,
    const float* __restrict__ stats, const float* __restrict__ g,
    const float* __restrict__ bt) {
  int idx = blockIdx.x * 256 + threadIdx.x;  // 524288 total
  int n = (idx >> 7) & 63;
  float mu = stats[n] * (1.f / 8192.f);
  float var = stats[64 + n] * (1.f / 8192.f) - mu * mu;
  float sc = rsqrtf(var + 128.f) * g[n];
  v[idx] = (v[idx] - mu) * sc + bt[n];
}

// ------------- g3: ev3[r] = v[r,:] . W + b  (De=1) -------------
__global__ __launch_bounds__(256) void k_ev3(const float* __restrict__ v,
    const float* __restrict__ W, const float* __restrict__ bias,
    float* __restrict__ ev3) {
  int r = blockIdx.x * 4 + (threadIdx.x >> 6);
  int lane = threadIdx.x & 63;
  float acc = v[r * 128 + lane] * W[lane] + v[r * 128 + 64 + lane] * W[64 + lane];
#pragma unroll
  for (int m = 1; m < 64; m <<= 1) acc += __shfl_xor(acc, m);
  if (lane == 0) ev3[r] = acc + bias[0];
}

// ------------- g3 edge: e3[b,i,j] = e.W3 + eb + ev3_i + ev3_j (no relu) -------------
__global__ __launch_bounds__(256) void k_edge_g3(const bf16_t* __restrict__ e_ws,
    const float* __restrict__ eW3, const float* __restrict__ eb3,
    const float* __restrict__ ev3, float* __restrict__ out_e,
    float* __restrict__ pve3) {
  __shared__ float W3[128];
  const int b = blockIdx.x >> 6, i = blockIdx.x & 63;
  const int tid = threadIdx.x;
  if (tid < 128) W3[tid] = eW3[tid];
  __syncthreads();
  const int j = tid >> 2, cs = (tid & 3) * 32;
  const bf16_t* ep = &e_ws[(size_t)((b * 64 + i) * 64 + j) * 128 + cs];
  float acc = 0.f;
#pragma unroll
  for (int t = 0; t < 4; ++t) {
    bf16x8 x = *(const bf16x8*)&ep[t * 8];
#pragma unroll
    for (int u = 0; u < 8; ++u) acc += (float)x[u] * W3[cs + t * 8 + u];
  }
  acc += __shfl_xor(acc, 1);
  acc += __shfl_xor(acc, 2);
  if ((tid & 3) == 0) {
    float s = acc + eb3[0] + ev3[b * 64 + i] + ev3[b * 64 + j];
    out_e[(b * 64 + i) * 64 + j] = s;
    atomicAdd(&pve3[b * 64 + j], s);
  }
}

// ------------- g3 v: v3[r] = pve3[r]*W[0] + v[r,:].W[1:] + b (no relu) -------------
__global__ __launch_bounds__(256) void k_v_g3(const float* __restrict__ v,
    const float* __restrict__ pve3, const float* __restrict__ vW,
    const float* __restrict__ vb, float* __restrict__ out_v) {
  int r = blockIdx.x * 4 + (threadIdx.x >> 6);
  int lane = threadIdx.x & 63;
  float acc = v[r * 128 + lane] * vW[1 + lane] + v[r * 128 + 64 + lane] * vW[65 + lane];
#pragma unroll
  for (int m = 1; m < 64; m <<= 1) acc += __shfl_xor(acc, m);
  if (lane == 0) out_v[r] = acc + pve3[r] * vW[0] + vb[0];
}

extern "C" void kernel_launch(void* const* d_in, const int* in_sizes, int n_in,
                              void* d_out, int out_size, void* d_ws, size_t ws_size,
                              hipStream_t stream) {
  const float* in_v    = (const float*)d_in[0];
  const float* in_e    = (const float*)d_in[1];
  const float* bn_in_g = (const float*)d_in[2];
  const float* bn_in_b = (const float*)d_in[3];
  const float* g1_evW  = (const float*)d_in[4];
  const float* g1_evb  = (const float*)d_in[5];
  const float* g1_eW   = (const float*)d_in[6];
  const float* g1_eb   = (const float*)d_in[7];
  const float* g1_vW   = (const float*)d_in[8];
  const float* g1_vb   = (const float*)d_in[9];
  const float* inn_evW = (const float*)d_in[10];
  const float* inn_evb = (const float*)d_in[11];
  const float* inn_eW  = (const float*)d_in[12];
  const float* inn_eb  = (const float*)d_in[13];
  const float* inn_vW  = (const float*)d_in[14];
  const float* inn_vb  = (const float*)d_in[15];
  const float* bn_g    = (const float*)d_in[16];
  const float* bn_b    = (const float*)d_in[17];
  const float* g3_evW  = (const float*)d_in[18];
  const float* g3_evb  = (const float*)d_in[19];
  const float* g3_eW   = (const float*)d_in[20];
  const float* g3_eb   = (const float*)d_in[21];
  const float* g3_vW   = (const float*)d_in[22];
  const float* g3_vb   = (const float*)d_in[23];

  char* ws = (char*)d_ws;
  bf16_t* e_ws = (bf16_t*)(ws);                       // 64MB : e as bf16
  float* v     = (float*)(ws + 67108864);             // 2MB
  float* ev    = (float*)(ws + 69206016);             // 2MB
  float* pve   = (float*)(ws + 71303168);             // 2MB
  float* v0    = (float*)(ws + 73400320);             // 512KB
  bf16_t* Wt   = (bf16_t*)(ws + 73924608);            // 128KB
  float* ev3   = (float*)(ws + 74055680);             // 16KB
  float* pve3  = (float*)(ws + 74072064);             // 16KB
  float* stats = (float*)(ws + 74088448);             // 512B

  float* out_v = (float*)d_out;          // [B,N,1] = 4096
  float* out_e = (float*)d_out + 4096;   // [B,N,N,1] = 262144

  k_bn_in<<<8, 256, 0, stream>>>(in_v, bn_in_g, bn_in_b, v0);
  k_prep_wt<<<256, 256, 0, stream>>>(inn_eW, Wt);

  // ---- g1 ----
  k_ev<32><<<512, 128, 0, stream>>>(v0, g1_evW, g1_evb, ev);
  k_edge_g1<<<4096, 256, 0, stream>>>(in_e, g1_eW, g1_eb, ev, e_ws, pve);
  k_v_g1<<<512, 128, 0, stream>>>(pve, v0, g1_vW, g1_vb, v);

  // ---- inner layers ----
  for (int l = 0; l < 4; ++l) {
    k_ev<128><<<512, 128, 0, stream>>>(v, inn_evW + l * 16384, inn_evb + l * 128, ev);
    k_edge_inner<<<4096, 256, 0, stream>>>(e_ws, Wt + l * 16384, inn_eb + l * 128, ev, pve);
    hipMemsetAsync(stats, 0, 512, stream);
    k_v_inner<<<512, 128, 0, stream>>>(pve, v, inn_vW + l * 32768, inn_vb + l * 128, stats);
    k_bn_apply<<<2048, 256, 0, stream>>>(v, stats, bn_g + l * 64, bn_b + l * 64);
  }

  // ---- g3 ----
  k_ev3<<<1024, 256, 0, stream>>>(v, g3_evW, g3_evb, ev3);
  hipMemsetAsync(pve3, 0, 16384, stream);
  k_edge_g3<<<4096, 256, 0, stream>>>(e_ws, g3_eW, g3_eb, ev3, out_e, pve3);
  k_v_g3<<<1024, 256, 0, stream>>>(v, pve3, g3_vW, g3_vb, out_v);
}

// Round 3
// 421.971 us; speedup vs baseline: 1.2689x; 1.2689x over previous
//
#include <hip/hip_runtime.h>
#include <hip/hip_bf16.h>

// GraphVertEdgeNet on MI355X. B=64, N=64, VF=32, EF=16, DV=DE=128, LN=4.
// e stored bf16 in ws (64MB). Edge kernels: MFMA orientation D[c][i]
// (A=W-frag m->c, B=e-frag n->i). ev_i+ev_j+eb folded into MFMA C-init
// (pre-barrier loads). e_old residual read from LDS. 2 j-columns per block.

typedef __bf16 bf16_t;
typedef __bf16 bf16x8 __attribute__((ext_vector_type(8)));
typedef __bf16 bf16x4 __attribute__((ext_vector_type(4)));
typedef float f32x4 __attribute__((ext_vector_type(4)));

// ---------------- input batchnorm: BatchNorm1d(N*VF) over batch ----------------
__global__ __launch_bounds__(256) void k_bn_in(const float* __restrict__ vin,
    const float* __restrict__ g, const float* __restrict__ bt,
    float* __restrict__ v0) {
  int ch = blockIdx.x * 256 + threadIdx.x;  // 0..2047
  float s = 0.f, s2 = 0.f;
  for (int b = 0; b < 64; ++b) { float x = vin[b * 2048 + ch]; s += x; s2 += x * x; }
  float mu = s * (1.f / 64.f);
  float var = s2 * (1.f / 64.f) - mu * mu;   // biased var
  float sc = rsqrtf(var + 1e-5f) * g[ch];
  float bb = bt[ch];
  for (int b = 0; b < 64; ++b) {
    float x = vin[b * 2048 + ch];
    v0[b * 2048 + ch] = (x - mu) * sc + bb;
  }
}

// ------------- weight prep: Wt[l][n][k] = eW[l][k][n] as bf16 -------------
__global__ __launch_bounds__(256) void k_prep_wt(const float* __restrict__ eW,
    bf16_t* __restrict__ Wt) {
  int idx = blockIdx.x * 256 + threadIdx.x;  // 4*128*128 = 65536
  int l = idx >> 14, r = idx & 16383, n = r >> 7, k = r & 127;
  Wt[idx] = (bf16_t)eW[(l << 14) + (k << 7) + n];
}

// ------------- ev = v_in @ W + bias : [4096,K] @ [K,128] -> [4096,128] -------------
template <int K>
__global__ __launch_bounds__(128) void k_ev(const float* __restrict__ v_in,
    const float* __restrict__ W, const float* __restrict__ bias,
    float* __restrict__ out) {
  __shared__ float rows[8][K];
  const int r0 = blockIdx.x * 8;
  const int c = threadIdx.x;  // 128 threads
  for (int idx = c; idx < 8 * K; idx += 128) {
    int rr = idx / K, kk = idx % K;
    rows[rr][kk] = v_in[(r0 + rr) * K + kk];
  }
  __syncthreads();
  float acc[8];
  const float bv = bias[c];
#pragma unroll
  for (int r = 0; r < 8; ++r) acc[r] = bv;
  for (int k4 = 0; k4 < K; k4 += 4) {
    float w0 = W[(k4 + 0) * 128 + c], w1 = W[(k4 + 1) * 128 + c];
    float w2 = W[(k4 + 2) * 128 + c], w3 = W[(k4 + 3) * 128 + c];
#pragma unroll
    for (int r = 0; r < 8; ++r) {
      float4 x = *(const float4*)&rows[r][k4];
      acc[r] += x.x * w0 + x.y * w1 + x.z * w2 + x.w * w3;
    }
  }
#pragma unroll
  for (int r = 0; r < 8; ++r) out[(r0 + r) * 128 + c] = acc[r];
}

// ------------- fused BN(prev layer) + ev matmul: normalizes v in place -------------
__global__ __launch_bounds__(128) void k_evbn(float* __restrict__ v,
    const float* __restrict__ stats, const float* __restrict__ g,
    const float* __restrict__ bt, const float* __restrict__ W,
    const float* __restrict__ bias, float* __restrict__ out) {
  __shared__ float rows[8][128];
  const int r0 = blockIdx.x * 8;
  const int c = threadIdx.x;
#pragma unroll
  for (int rr = 0; rr < 8; ++rr) {
    int n = (r0 + rr) & 63;
    float mu = stats[n] * (1.f / 8192.f);
    float var = stats[64 + n] * (1.f / 8192.f) - mu * mu;
    float sc = rsqrtf(var + 128.f) * g[n];
    float x = (v[(r0 + rr) * 128 + c] - mu) * sc + bt[n];
    rows[rr][c] = x;
    v[(r0 + rr) * 128 + c] = x;  // normalized v for residual/concat/g3
  }
  __syncthreads();
  float acc[8];
  const float bv = bias[c];
#pragma unroll
  for (int r = 0; r < 8; ++r) acc[r] = bv;
  for (int k4 = 0; k4 < 128; k4 += 4) {
    float w0 = W[(k4 + 0) * 128 + c], w1 = W[(k4 + 1) * 128 + c];
    float w2 = W[(k4 + 2) * 128 + c], w3 = W[(k4 + 3) * 128 + c];
#pragma unroll
    for (int r = 0; r < 8; ++r) {
      float4 x = *(const float4*)&rows[r][k4];
      acc[r] += x.x * w0 + x.y * w1 + x.z * w2 + x.w * w3;
    }
  }
#pragma unroll
  for (int r = 0; r < 8; ++r) out[(r0 + r) * 128 + c] = acc[r];
}

// ------------- g1 edge pass (MFMA, K 16->32 zero-pad, 2 j per block) -------------
__global__ __launch_bounds__(256) void k_edge_g1(const float* __restrict__ e0,
    const float* __restrict__ eW, const float* __restrict__ eb,
    const float* __restrict__ ev, bf16_t* __restrict__ e_ws,
    float* __restrict__ pve) {
  __shared__ bf16_t A0s[2][64][40];
  __shared__ bf16_t Os[2][64][136];
  const int b = blockIdx.x >> 5, j0 = (blockIdx.x & 31) * 2;
  const int tid = threadIdx.x;
  const int lane = tid & 63, w = tid >> 6;
  const int quad = lane >> 4, l16 = lane & 15;
  // stage e0 two columns -> bf16, zero-pad K 16..31
#pragma unroll
  for (int t = 0; t < 2; ++t) {
    int idx = tid + t * 256;
    int row = idx >> 3, off = (idx & 7) * 4;  // off in floats 0..31
    int jc = off >> 4, k = off & 15;
    f32x4 x = *(const f32x4*)&e0[((b * 64 + row) * 64 + j0) * 16 + off];
    bf16x4 y;
#pragma unroll
    for (int r = 0; r < 4; ++r) y[r] = (bf16_t)x[r];
    *(bf16x4*)&A0s[jc][row][k] = y;
    bf16x4 z = {(bf16_t)0.f, (bf16_t)0.f, (bf16_t)0.f, (bf16_t)0.f};
    *(bf16x4*)&A0s[jc][row][16 + k] = z;
  }
  const int c0[2] = {w * 32 + quad * 4, w * 32 + 16 + quad * 4};
  // W A-frags: A[m=c][k=quad*8+jj], zero for k>=16
  bf16x8 wf[2];
#pragma unroll
  for (int nt = 0; nt < 2; ++nt) {
    const int c = w * 32 + nt * 16 + l16;
#pragma unroll
    for (int jj = 0; jj < 8; ++jj)
      wf[nt][jj] = (quad < 2) ? (bf16_t)eW[(quad * 8 + jj) * 128 + c] : (bf16_t)0.f;
  }
  // acc init = eb + ev_j + ev_i (all folded into MFMA C)
  f32x4 acc[2][4][2];
  {
    f32x4 ebv[2], evj[2][2], evi[4][2];
#pragma unroll
    for (int nt = 0; nt < 2; ++nt) {
      ebv[nt] = *(const f32x4*)&eb[c0[nt]];
#pragma unroll
      for (int jc = 0; jc < 2; ++jc)
        evj[jc][nt] = *(const f32x4*)&ev[(b * 64 + j0 + jc) * 128 + c0[nt]];
#pragma unroll
      for (int mt = 0; mt < 4; ++mt)
        evi[mt][nt] = *(const f32x4*)&ev[(b * 64 + mt * 16 + l16) * 128 + c0[nt]];
    }
#pragma unroll
    for (int jc = 0; jc < 2; ++jc)
#pragma unroll
      for (int mt = 0; mt < 4; ++mt)
#pragma unroll
        for (int nt = 0; nt < 2; ++nt)
          acc[jc][mt][nt] = ebv[nt] + evj[jc][nt] + evi[mt][nt];
  }
  __syncthreads();
#pragma unroll
  for (int jc = 0; jc < 2; ++jc) {
#pragma unroll
    for (int mt = 0; mt < 4; ++mt) {
      bf16x8 ef = *(const bf16x8*)&A0s[jc][mt * 16 + l16][quad * 8];
#pragma unroll
      for (int nt = 0; nt < 2; ++nt)
        acc[jc][mt][nt] = __builtin_amdgcn_mfma_f32_16x16x32_bf16(wf[nt], ef, acc[jc][mt][nt], 0, 0, 0);
    }
  }
  // epilogue: relu, pve, pack to Os
#pragma unroll
  for (int jc = 0; jc < 2; ++jc) {
#pragma unroll
    for (int nt = 0; nt < 2; ++nt) {
      f32x4 ps = {0.f, 0.f, 0.f, 0.f};
#pragma unroll
      for (int mt = 0; mt < 4; ++mt) {
        const int i = mt * 16 + l16;
        bf16x4 outv;
#pragma unroll
        for (int r = 0; r < 4; ++r) {
          float vv = fmaxf(acc[jc][mt][nt][r], 0.f);
          ps[r] += vv;
          outv[r] = (bf16_t)vv;
        }
        *(bf16x4*)&Os[jc][i][c0[nt]] = outv;
      }
#pragma unroll
      for (int m = 1; m <= 8; m <<= 1) {
#pragma unroll
        for (int r = 0; r < 4; ++r) ps[r] += __shfl_xor(ps[r], m);
      }
      if (l16 == 0) *(f32x4*)&pve[(b * 64 + j0 + jc) * 128 + c0[nt]] = ps;
    }
  }
  __syncthreads();
#pragma unroll
  for (int t = 0; t < 8; ++t) {  // coalesced copy-out: 512B per row (2 cols)
    int idx = tid + t * 256;
    int row = idx >> 5, off = (idx & 31) * 8;
    int jc = off >> 7, c = off & 127;
    *(int4*)&e_ws[((b * 64 + row) * 64 + j0) * 128 + off] = *(const int4*)&Os[jc][row][c];
  }
}

// ------------- g1 v pass: relu(concat(pve[128], v0[32]) @ [160,128]) -------------
__global__ __launch_bounds__(128) void k_v_g1(const float* __restrict__ pve,
    const float* __restrict__ v0, const float* __restrict__ vW,
    const float* __restrict__ vb, float* __restrict__ v) {
  __shared__ float in[8][160];
  const int r0 = blockIdx.x * 8;
  const int c = threadIdx.x;
#pragma unroll
  for (int t = 0; t < 8; ++t) {
    int idx = c + t * 128;
    int rr = idx >> 7, k = idx & 127;
    in[rr][k] = pve[(r0 + rr) * 128 + k];
  }
#pragma unroll
  for (int t = 0; t < 2; ++t) {
    int idx = c + t * 128;
    int rr = idx >> 5, k = idx & 31;
    in[rr][128 + k] = v0[(r0 + rr) * 32 + k];
  }
  __syncthreads();
  float acc[8];
  const float bv = vb[c];
#pragma unroll
  for (int r = 0; r < 8; ++r) acc[r] = bv;
  for (int k4 = 0; k4 < 160; k4 += 4) {
    float w0 = vW[(k4 + 0) * 128 + c], w1 = vW[(k4 + 1) * 128 + c];
    float w2 = vW[(k4 + 2) * 128 + c], w3 = vW[(k4 + 3) * 128 + c];
#pragma unroll
    for (int r = 0; r < 8; ++r) {
      float4 x = *(const float4*)&in[r][k4];
      acc[r] += x.x * w0 + x.y * w1 + x.z * w2 + x.w * w3;
    }
  }
#pragma unroll
  for (int r = 0; r < 8; ++r) v[(r0 + r) * 128 + c] = fmaxf(acc[r], 0.f);
}

// ------------- inner edge pass (MFMA, D[c][i], 2 j per block) -------------
// e += relu(e@W + eb + ev_i + ev_j); pve = per-column sum of pre-residual.
__global__ __launch_bounds__(256) void k_edge_inner(bf16_t* __restrict__ e_ws,
    const bf16_t* __restrict__ Wt, const float* __restrict__ eb,
    const float* __restrict__ ev, float* __restrict__ pve) {
  __shared__ bf16_t As[2][64][136];   // +8 pad per row
  const int b = blockIdx.x >> 5, j0 = (blockIdx.x & 31) * 2;
  const int tid = threadIdx.x;
  const int lane = tid & 63, w = tid >> 6;
  const int quad = lane >> 4, l16 = lane & 15;
  // stage 2 columns: 512B contiguous per row
  int4 stg[8];
#pragma unroll
  for (int t = 0; t < 8; ++t) {
    int idx = tid + t * 256;
    int row = idx >> 5, off = (idx & 31) * 8;
    stg[t] = *(const int4*)&e_ws[((b * 64 + row) * 64 + j0) * 128 + off];
  }
  // W A-frags in registers (L2-hot): A[m=c][k]
  bf16x8 wf[2][4];
#pragma unroll
  for (int nt = 0; nt < 2; ++nt)
#pragma unroll
    for (int ks = 0; ks < 4; ++ks)
      wf[nt][ks] = *(const bf16x8*)&Wt[(w * 32 + nt * 16 + l16) * 128 + ks * 32 + quad * 8];
  const int c0[2] = {w * 32 + quad * 4, w * 32 + 16 + quad * 4};
  // acc init = eb + ev_j + ev_i (folded into MFMA C; loads pre-barrier)
  f32x4 acc[2][4][2];
  {
    f32x4 ebv[2], evj[2][2], evi[4][2];
#pragma unroll
    for (int nt = 0; nt < 2; ++nt) {
      ebv[nt] = *(const f32x4*)&eb[c0[nt]];
#pragma unroll
      for (int jc = 0; jc < 2; ++jc)
        evj[jc][nt] = *(const f32x4*)&ev[(b * 64 + j0 + jc) * 128 + c0[nt]];
#pragma unroll
      for (int mt = 0; mt < 4; ++mt)
        evi[mt][nt] = *(const f32x4*)&ev[(b * 64 + mt * 16 + l16) * 128 + c0[nt]];
    }
#pragma unroll
    for (int jc = 0; jc < 2; ++jc)
#pragma unroll
      for (int mt = 0; mt < 4; ++mt)
#pragma unroll
        for (int nt = 0; nt < 2; ++nt)
          acc[jc][mt][nt] = ebv[nt] + evj[jc][nt] + evi[mt][nt];
  }
#pragma unroll
  for (int t = 0; t < 8; ++t) {
    int idx = tid + t * 256;
    int row = idx >> 5, off = (idx & 31) * 8;
    *(int4*)&As[off >> 7][row][off & 127] = stg[t];
  }
  __syncthreads();
  // MFMA: D[c][i] = sum_k Wt[c][k] * e[i][k]  (64 MFMA per block)
#pragma unroll
  for (int ks = 0; ks < 4; ++ks) {
    bf16x8 ef[2][4];
#pragma unroll
    for (int jc = 0; jc < 2; ++jc)
#pragma unroll
      for (int mt = 0; mt < 4; ++mt)
        ef[jc][mt] = *(const bf16x8*)&As[jc][mt * 16 + l16][ks * 32 + quad * 8];
#pragma unroll
    for (int jc = 0; jc < 2; ++jc)
#pragma unroll
      for (int mt = 0; mt < 4; ++mt)
#pragma unroll
        for (int nt = 0; nt < 2; ++nt)
          acc[jc][mt][nt] = __builtin_amdgcn_mfma_f32_16x16x32_bf16(wf[nt][ks], ef[jc][mt], acc[jc][mt][nt], 0, 0, 0);
  }
  __syncthreads();  // all As reads done before in-place update
  // epilogue: relu, pve, residual from LDS, packed b64 writes to own cells
#pragma unroll
  for (int jc = 0; jc < 2; ++jc) {
#pragma unroll
    for (int nt = 0; nt < 2; ++nt) {
      f32x4 ps = {0.f, 0.f, 0.f, 0.f};
#pragma unroll
      for (int mt = 0; mt < 4; ++mt) {
        const int i = mt * 16 + l16;
        bf16x4 eo = *(const bf16x4*)&As[jc][i][c0[nt]];
        bf16x4 outv;
#pragma unroll
        for (int r = 0; r < 4; ++r) {
          float vv = fmaxf(acc[jc][mt][nt][r], 0.f);
          ps[r] += vv;                            // pve is pre-residual
          outv[r] = (bf16_t)(vv + (float)eo[r]);  // residual
        }
        *(bf16x4*)&As[jc][i][c0[nt]] = outv;
      }
#pragma unroll
      for (int m = 1; m <= 8; m <<= 1) {  // reduce over i (l16 lanes)
#pragma unroll
        for (int r = 0; r < 4; ++r) ps[r] += __shfl_xor(ps[r], m);
      }
      if (l16 == 0) *(f32x4*)&pve[(b * 64 + j0 + jc) * 128 + c0[nt]] = ps;
    }
  }
  __syncthreads();
#pragma unroll
  for (int t = 0; t < 8; ++t) {  // coalesced write-back: 512B per row
    int idx = tid + t * 256;
    int row = idx >> 5, off = (idx & 31) * 8;
    *(int4*)&e_ws[((b * 64 + row) * 64 + j0) * 128 + off] = *(const int4*)&As[off >> 7][row][off & 127];
  }
}

// ------------- inner v pass: v = relu(concat(pve,v)@[256,128]+vb) + v; BN partial stats -------------
__global__ __launch_bounds__(128) void k_v_inner(const float* __restrict__ pve,
    float* __restrict__ v, const float* __restrict__ vW,
    const float* __restrict__ vb, float* __restrict__ stats) {
  __shared__ float in[8][256];
  __shared__ float outs[8][132];  // +4 pad
  const int r0 = blockIdx.x * 8;
  const int c = threadIdx.x;
#pragma unroll
  for (int t = 0; t < 8; ++t) {
    int idx = c + t * 128;
    int rr = idx >> 7, k = idx & 127;
    in[rr][k] = pve[(r0 + rr) * 128 + k];
    in[rr][128 + k] = v[(r0 + rr) * 128 + k];
  }
  __syncthreads();
  float acc[8];
  const float bv = vb[c];
#pragma unroll
  for (int r = 0; r < 8; ++r) acc[r] = bv;
  for (int k4 = 0; k4 < 256; k4 += 4) {
    float w0 = vW[(k4 + 0) * 128 + c], w1 = vW[(k4 + 1) * 128 + c];
    float w2 = vW[(k4 + 2) * 128 + c], w3 = vW[(k4 + 3) * 128 + c];
#pragma unroll
    for (int r = 0; r < 8; ++r) {
      float4 x = *(const float4*)&in[r][k4];
      acc[r] += x.x * w0 + x.y * w1 + x.z * w2 + x.w * w3;
    }
  }
#pragma unroll
  for (int r = 0; r < 8; ++r) {
    float val = fmaxf(acc[r], 0.f) + in[r][128 + c];  // relu + residual
    outs[r][c] = val;
    v[(r0 + r) * 128 + c] = val;
  }
  __syncthreads();
  if (c < 8) {  // per-(b,n) partial sums for BN stats over (B,D)
    float s = 0.f, s2 = 0.f;
    for (int k = 0; k < 128; ++k) { float x = outs[c][k]; s += x; s2 += x * x; }
    int n = (r0 + c) & 63;
    atomicAdd(&stats[n], s);
    atomicAdd(&stats[64 + n], s2);
  }
}

// ------------- BN-inner apply (final layer only) -------------
__global__ __launch_bounds__(256) void k_bn_apply(float* __restrict__ v,
    const float* __restrict__ stats, const float* __restrict__ g,
    const float* __restrict__ bt) {
  int idx = blockIdx.x * 256 + threadIdx.x;  // 524288 total
  int n = (idx >> 7) & 63;
  float mu = stats[n] * (1.f / 8192.f);
  float var = stats[64 + n] * (1.f / 8192.f) - mu * mu;
  float sc = rsqrtf(var + 128.f) * g[n];
  v[idx] = (v[idx] - mu) * sc + bt[n];
}

// ------------- g3: ev3[r] = v[r,:] . W + b  (De=1) -------------
__global__ __launch_bounds__(256) void k_ev3(const float* __restrict__ v,
    const float* __restrict__ W, const float* __restrict__ bias,
    float* __restrict__ ev3) {
  int r = blockIdx.x * 4 + (threadIdx.x >> 6);
  int lane = threadIdx.x & 63;
  float acc = v[r * 128 + lane] * W[lane] + v[r * 128 + 64 + lane] * W[64 + lane];
#pragma unroll
  for (int m = 1; m < 64; m <<= 1) acc += __shfl_xor(acc, m);
  if (lane == 0) ev3[r] = acc + bias[0];
}

// ------------- g3 edge: e3[b,i,j] = e.W3 + eb + ev3_i + ev3_j (no relu) -------------
__global__ __launch_bounds__(256) void k_edge_g3(const bf16_t* __restrict__ e_ws,
    const float* __restrict__ eW3, const float* __restrict__ eb3,
    const float* __restrict__ ev3, float* __restrict__ out_e,
    float* __restrict__ pve3) {
  __shared__ float W3[128];
  const int b = blockIdx.x >> 6, i = blockIdx.x & 63;
  const int tid = threadIdx.x;
  if (tid < 128) W3[tid] = eW3[tid];
  __syncthreads();
  const int j = tid >> 2, cs = (tid & 3) * 32;
  const bf16_t* ep = &e_ws[(size_t)((b * 64 + i) * 64 + j) * 128 + cs];
  float acc = 0.f;
#pragma unroll
  for (int t = 0; t < 4; ++t) {
    bf16x8 x = *(const bf16x8*)&ep[t * 8];
#pragma unroll
    for (int u = 0; u < 8; ++u) acc += (float)x[u] * W3[cs + t * 8 + u];
  }
  acc += __shfl_xor(acc, 1);
  acc += __shfl_xor(acc, 2);
  if ((tid & 3) == 0) {
    float s = acc + eb3[0] + ev3[b * 64 + i] + ev3[b * 64 + j];
    out_e[(b * 64 + i) * 64 + j] = s;
    atomicAdd(&pve3[b * 64 + j], s);
  }
}

// ------------- g3 v: v3[r] = pve3[r]*W[0] + v[r,:].W[1:] + b (no relu) -------------
__global__ __launch_bounds__(256) void k_v_g3(const float* __restrict__ v,
    const float* __restrict__ pve3, const float* __restrict__ vW,
    const float* __restrict__ vb, float* __restrict__ out_v) {
  int r = blockIdx.x * 4 + (threadIdx.x >> 6);
  int lane = threadIdx.x & 63;
  float acc = v[r * 128 + lane] * vW[1 + lane] + v[r * 128 + 64 + lane] * vW[65 + lane];
#pragma unroll
  for (int m = 1; m < 64; m <<= 1) acc += __shfl_xor(acc, m);
  if (lane == 0) out_v[r] = acc + pve3[r] * vW[0] + vb[0];
}

extern "C" void kernel_launch(void* const* d_in, const int* in_sizes, int n_in,
                              void* d_out, int out_size, void* d_ws, size_t ws_size,
                              hipStream_t stream) {
  const float* in_v    = (const float*)d_in[0];
  const float* in_e    = (const float*)d_in[1];
  const float* bn_in_g = (const float*)d_in[2];
  const float* bn_in_b = (const float*)d_in[3];
  const float* g1_evW  = (const float*)d_in[4];
  const float* g1_evb  = (const float*)d_in[5];
  const float* g1_eW   = (const float*)d_in[6];
  const float* g1_eb   = (const float*)d_in[7];
  const float* g1_vW   = (const float*)d_in[8];
  const float* g1_vb   = (const float*)d_in[9];
  const float* inn_evW = (const float*)d_in[10];
  const float* inn_evb = (const float*)d_in[11];
  const float* inn_eW  = (const float*)d_in[12];
  const float* inn_eb  = (const float*)d_in[13];
  const float* inn_vW  = (const float*)d_in[14];
  const float* inn_vb  = (const float*)d_in[15];
  const float* bn_g    = (const float*)d_in[16];
  const float* bn_b    = (const float*)d_in[17];
  const float* g3_evW  = (const float*)d_in[18];
  const float* g3_evb  = (const float*)d_in[19];
  const float* g3_eW   = (const float*)d_in[20];
  const float* g3_eb   = (const float*)d_in[21];
  const float* g3_vW   = (const float*)d_in[22];
  const float* g3_vb   = (const float*)d_in[23];

  char* ws = (char*)d_ws;
  bf16_t* e_ws = (bf16_t*)(ws);                       // 64MB : e as bf16
  float* v     = (float*)(ws + 67108864);             // 2MB
  float* ev    = (float*)(ws + 69206016);             // 2MB
  float* pve   = (float*)(ws + 71303168);             // 2MB
  float* v0    = (float*)(ws + 73400320);             // 512KB
  bf16_t* Wt   = (bf16_t*)(ws + 73924608);            // 128KB
  float* ev3   = (float*)(ws + 74055680);             // 16KB
  // zero region: pve3 (16KB) + 4x stats (512B each) -> one memset
  float* pve3  = (float*)(ws + 74072064);             // 16KB
  float* stats = (float*)(ws + 74088448);             // 2KB (4 layers x 128 f32)

  float* out_v = (float*)d_out;          // [B,N,1] = 4096
  float* out_e = (float*)d_out + 4096;   // [B,N,N,1] = 262144

  hipMemsetAsync(pve3, 0, 16384 + 2048, stream);
  k_bn_in<<<8, 256, 0, stream>>>(in_v, bn_in_g, bn_in_b, v0);
  k_prep_wt<<<256, 256, 0, stream>>>(inn_eW, Wt);

  // ---- g1 ----
  k_ev<32><<<512, 128, 0, stream>>>(v0, g1_evW, g1_evb, ev);
  k_edge_g1<<<2048, 256, 0, stream>>>(in_e, g1_eW, g1_eb, ev, e_ws, pve);
  k_v_g1<<<512, 128, 0, stream>>>(pve, v0, g1_vW, g1_vb, v);

  // ---- inner layers (BN of layer l-1 fused into layer l's ev kernel) ----
  for (int l = 0; l < 4; ++l) {
    if (l == 0)
      k_ev<128><<<512, 128, 0, stream>>>(v, inn_evW, inn_evb, ev);
    else
      k_evbn<<<512, 128, 0, stream>>>(v, stats + (l - 1) * 128, bn_g + (l - 1) * 64,
                                      bn_b + (l - 1) * 64, inn_evW + l * 16384,
                                      inn_evb + l * 128, ev);
    k_edge_inner<<<2048, 256, 0, stream>>>(e_ws, Wt + l * 16384, inn_eb + l * 128, ev, pve);
    k_v_inner<<<512, 128, 0, stream>>>(pve, v, inn_vW + l * 32768, inn_vb + l * 128,
                                       stats + l * 128);
  }
  k_bn_apply<<<2048, 256, 0, stream>>>(v, stats + 3 * 128, bn_g + 192, bn_b + 192);

  // ---- g3 ----
  k_ev3<<<1024, 256, 0, stream>>>(v, g3_evW, g3_evb, ev3);
  k_edge_g3<<<4096, 256, 0, stream>>>(e_ws, g3_eW, g3_eb, ev3, out_e, pve3);
  k_v_g3<<<1024, 256, 0, stream>>>(v, pve3, g3_vW, g3_vb, out_v);
}